// Round 4
// baseline (5164.013 us; speedup 1.0000x reference)
//
#include <hip/hip_runtime.h>

#define N_NODES 50000
#define N_EDGES 800000
#define N_GRAPHS 512
#define D_IN 128
#define D_EDGE 32
#define D_HID 128
#define D_GLOB 64

__device__ __forceinline__ int clampi(int v, int hi) {   // [0, hi)
    return v < 0 ? 0 : (v >= hi ? hi - 1 : v);
}

// ---------------------------------------------------------------------------
// Edge kernel: 32 edges/block, 256 threads. Gather [src|dest|attr] (288 fp32)
// rows to LDS, MLP 288->128 relu ->128 relu, scatter-add msg to agg[dest]
// with native fp32 atomics. agg aliases the x_weights output region.
// Thread (tx,ty): tx=tid&15 -> cols tx*8..+8, ty=tid>>4 -> rows ty*2..+2.
// ---------------------------------------------------------------------------
__global__ __launch_bounds__(256) void edge_kernel(
    const float* __restrict__ x, const int* __restrict__ eidx,
    const float* __restrict__ eattr,
    const float* __restrict__ We1, const float* __restrict__ be1,
    const float* __restrict__ We2, const float* __restrict__ be2,
    float* __restrict__ agg)
{
    __shared__ alignas(16) float sA[32][292];   // 288 + 4 pad
    __shared__ alignas(16) float sW[32][128];
    __shared__ alignas(16) float sH[32][132];   // 128 + 4 pad
    __shared__ int sDest[32];

    const int tid = threadIdx.x;
    const int tx = tid & 15;
    const int ty = tid >> 4;
    const int e0 = blockIdx.x * 32;

    if (tid < 32) sDest[tid] = clampi(eidx[N_EDGES + e0 + tid], N_NODES);

    // gather: 32 edges x 72 float4 (32 src + 32 dest + 8 attr) = 2304 = 9*256
    #pragma unroll
    for (int it = 0; it < 9; ++it) {
        int idx = it * 256 + tid;
        int e = idx / 72;
        int c = idx - e * 72;
        const float* p;
        if (c < 32)      p = x + (size_t)clampi(eidx[e0 + e], N_NODES) * 128 + c * 4;
        else if (c < 64) p = x + (size_t)clampi(eidx[N_EDGES + e0 + e], N_NODES) * 128 + (c - 32) * 4;
        else             p = eattr + (size_t)(e0 + e) * 32 + (c - 64) * 4;
        *(float4*)&sA[e][c * 4] = *(const float4*)p;
    }

    float acc[2][8];
    #pragma unroll
    for (int i = 0; i < 2; ++i)
        #pragma unroll
        for (int j = 0; j < 8; ++j) acc[i][j] = 0.f;

    // ---- layer 1: K = 288 (9 chunks of 32) ----
    for (int kc = 0; kc < 9; ++kc) {
        __syncthreads();
        #pragma unroll
        for (int it = 0; it < 4; ++it) {
            int idx = it * 256 + tid;
            int r = idx >> 5, c4 = idx & 31;
            *(float4*)&sW[r][c4 * 4] = *(const float4*)&We1[(size_t)(kc * 32 + r) * 128 + c4 * 4];
        }
        __syncthreads();
        #pragma unroll
        for (int k = 0; k < 32; ++k) {
            float4 w0 = *(float4*)&sW[k][tx * 8];
            float4 w1 = *(float4*)&sW[k][tx * 8 + 4];
            float w[8] = {w0.x, w0.y, w0.z, w0.w, w1.x, w1.y, w1.z, w1.w};
            float a0 = sA[ty * 2 + 0][kc * 32 + k];
            float a1 = sA[ty * 2 + 1][kc * 32 + k];
            #pragma unroll
            for (int j = 0; j < 8; ++j) {
                acc[0][j] = fmaf(a0, w[j], acc[0][j]);
                acc[1][j] = fmaf(a1, w[j], acc[1][j]);
            }
        }
    }

    // bias + relu -> sH, reset acc
    #pragma unroll
    for (int j = 0; j < 8; ++j) {
        float b = be1[tx * 8 + j];
        #pragma unroll
        for (int i = 0; i < 2; ++i) {
            sH[ty * 2 + i][tx * 8 + j] = fmaxf(acc[i][j] + b, 0.f);
            acc[i][j] = 0.f;
        }
    }

    // ---- layer 2: K = 128 (4 chunks of 32) ----
    for (int kc = 0; kc < 4; ++kc) {
        __syncthreads();
        #pragma unroll
        for (int it = 0; it < 4; ++it) {
            int idx = it * 256 + tid;
            int r = idx >> 5, c4 = idx & 31;
            *(float4*)&sW[r][c4 * 4] = *(const float4*)&We2[(size_t)(kc * 32 + r) * 128 + c4 * 4];
        }
        __syncthreads();
        #pragma unroll
        for (int k = 0; k < 32; ++k) {
            float4 w0 = *(float4*)&sW[k][tx * 8];
            float4 w1 = *(float4*)&sW[k][tx * 8 + 4];
            float w[8] = {w0.x, w0.y, w0.z, w0.w, w1.x, w1.y, w1.z, w1.w};
            float a0 = sH[ty * 2 + 0][kc * 32 + k];
            float a1 = sH[ty * 2 + 1][kc * 32 + k];
            #pragma unroll
            for (int j = 0; j < 8; ++j) {
                acc[0][j] = fmaf(a0, w[j], acc[0][j]);
                acc[1][j] = fmaf(a1, w[j], acc[1][j]);
            }
        }
    }

    // bias + relu + fp32 atomic scatter
    #pragma unroll
    for (int i = 0; i < 2; ++i) {
        int d = sDest[ty * 2 + i];
        float* dst = agg + (size_t)d * 128 + tx * 8;
        #pragma unroll
        for (int j = 0; j < 8; ++j) {
            float b = be2[tx * 8 + j];
            float v = fmaxf(acc[i][j] + b, 0.f);
            unsafeAtomicAdd(dst + j, v);
        }
    }
}

// ---------------------------------------------------------------------------
// Fused node+global kernel: one block (256 threads) per graph. batch is
// sorted -> graph g owns contiguous [start, end). Per 32-node tile: gather
// [x | agg] to LDS, gate GEMM (K=256) -> sigmoid -> write x_weights (over-
// writes agg rows of THIS tile only, already staged in LDS), update GEMM ->
// x_new = gate*relu(.), accumulate pooled sum in registers. Epilogue:
// LDS-reduce pooled, compute this graph's u_new row. No global scratch.
// ---------------------------------------------------------------------------
__global__ __launch_bounds__(256) void node_global_kernel(
    const float* __restrict__ x, const float* __restrict__ agg,
    const int* __restrict__ batch,
    const float* __restrict__ Wg, const float* __restrict__ bg,
    const float* __restrict__ Wn, const float* __restrict__ bn,
    const float* __restrict__ u, const float* __restrict__ Wu,
    const float* __restrict__ bu,
    float* __restrict__ xw_out, float* __restrict__ out)
{
    __shared__ alignas(16) float sA[32][260];   // 256 + 4 pad
    __shared__ alignas(16) float sW[32][128];
    __shared__ alignas(16) float redu[16][132];
    __shared__ alignas(16) float cat[192];
    __shared__ int sRange[2];

    const int tid = threadIdx.x;
    const int tx = tid & 15;
    const int ty = tid >> 4;
    const int g = blockIdx.x;

    if (tid == 0) {
        int lo = 0, hi = N_NODES;
        while (lo < hi) { int m = (lo + hi) >> 1; if (batch[m] < g) lo = m + 1; else hi = m; }
        sRange[0] = lo;
        hi = N_NODES;
        while (lo < hi) { int m = (lo + hi) >> 1; if (batch[m] < g + 1) lo = m + 1; else hi = m; }
        sRange[1] = lo;
    }
    __syncthreads();
    const int start = sRange[0];
    const int end   = sRange[1];

    float pool_acc[8];
    #pragma unroll
    for (int j = 0; j < 8; ++j) pool_acc[j] = 0.f;

    for (int n0 = start; n0 < end; n0 += 32) {
        // gather x -> sA[:, 0:128] and agg -> sA[:, 128:256]
        #pragma unroll
        for (int it = 0; it < 4; ++it) {
            int idx = it * 256 + tid;
            int r = idx >> 5, c = idx & 31;
            float4 v = make_float4(0.f, 0.f, 0.f, 0.f);
            if (n0 + r < end) v = *(const float4*)&x[(size_t)(n0 + r) * 128 + c * 4];
            *(float4*)&sA[r][c * 4] = v;
        }
        #pragma unroll
        for (int it = 0; it < 4; ++it) {
            int idx = it * 256 + tid;
            int r = idx >> 5, c = idx & 31;
            float4 v = make_float4(0.f, 0.f, 0.f, 0.f);
            if (n0 + r < end) v = *(const float4*)&agg[(size_t)(n0 + r) * 128 + c * 4];
            *(float4*)&sA[r][128 + c * 4] = v;
        }

        float acc[2][8];
        #pragma unroll
        for (int i = 0; i < 2; ++i)
            #pragma unroll
            for (int j = 0; j < 8; ++j) acc[i][j] = 0.f;

        // ---- gate GEMM: K = 256 ----
        for (int kc = 0; kc < 8; ++kc) {
            __syncthreads();
            #pragma unroll
            for (int it = 0; it < 4; ++it) {
                int idx = it * 256 + tid;
                int r = idx >> 5, c4 = idx & 31;
                *(float4*)&sW[r][c4 * 4] = *(const float4*)&Wg[(size_t)(kc * 32 + r) * 128 + c4 * 4];
            }
            __syncthreads();
            #pragma unroll
            for (int k = 0; k < 32; ++k) {
                float4 w0 = *(float4*)&sW[k][tx * 8];
                float4 w1 = *(float4*)&sW[k][tx * 8 + 4];
                float w[8] = {w0.x, w0.y, w0.z, w0.w, w1.x, w1.y, w1.z, w1.w};
                float a0 = sA[ty * 2 + 0][kc * 32 + k];
                float a1 = sA[ty * 2 + 1][kc * 32 + k];
                #pragma unroll
                for (int j = 0; j < 8; ++j) {
                    acc[0][j] = fmaf(a0, w[j], acc[0][j]);
                    acc[1][j] = fmaf(a1, w[j], acc[1][j]);
                }
            }
        }

        // sigmoid -> gates; write x_weights rows of this tile (n < end)
        float gate[2][8];
        #pragma unroll
        for (int i = 0; i < 2; ++i) {
            int n = n0 + ty * 2 + i;
            #pragma unroll
            for (int j = 0; j < 8; ++j) {
                float v = acc[i][j] + bg[tx * 8 + j];
                gate[i][j] = 1.0f / (1.0f + __expf(-v));
                acc[i][j] = 0.f;
            }
            if (n < end) {
                float4 g0 = make_float4(gate[i][0], gate[i][1], gate[i][2], gate[i][3]);
                float4 g1 = make_float4(gate[i][4], gate[i][5], gate[i][6], gate[i][7]);
                *(float4*)&xw_out[(size_t)n * 128 + tx * 8]     = g0;
                *(float4*)&xw_out[(size_t)n * 128 + tx * 8 + 4] = g1;
            }
        }

        // ---- update GEMM: K = 256 ----
        for (int kc = 0; kc < 8; ++kc) {
            __syncthreads();
            #pragma unroll
            for (int it = 0; it < 4; ++it) {
                int idx = it * 256 + tid;
                int r = idx >> 5, c4 = idx & 31;
                *(float4*)&sW[r][c4 * 4] = *(const float4*)&Wn[(size_t)(kc * 32 + r) * 128 + c4 * 4];
            }
            __syncthreads();
            #pragma unroll
            for (int k = 0; k < 32; ++k) {
                float4 w0 = *(float4*)&sW[k][tx * 8];
                float4 w1 = *(float4*)&sW[k][tx * 8 + 4];
                float w[8] = {w0.x, w0.y, w0.z, w0.w, w1.x, w1.y, w1.z, w1.w};
                float a0 = sA[ty * 2 + 0][kc * 32 + k];
                float a1 = sA[ty * 2 + 1][kc * 32 + k];
                #pragma unroll
                for (int j = 0; j < 8; ++j) {
                    acc[0][j] = fmaf(a0, w[j], acc[0][j]);
                    acc[1][j] = fmaf(a1, w[j], acc[1][j]);
                }
            }
        }

        // x_new = gate * relu(acc + bn); accumulate pooled (valid rows only)
        #pragma unroll
        for (int i = 0; i < 2; ++i) {
            int n = n0 + ty * 2 + i;
            if (n < end) {
                #pragma unroll
                for (int j = 0; j < 8; ++j) {
                    float v = fmaxf(acc[i][j] + bn[tx * 8 + j], 0.f);
                    pool_acc[j] += gate[i][j] * v;
                }
            }
        }
        __syncthreads();  // protect sA/sW before next tile's gathers
    }

    // ---- reduce pooled partials across ty ----
    #pragma unroll
    for (int j = 0; j < 8; ++j) redu[ty][tx * 8 + j] = pool_acc[j];
    __syncthreads();
    #pragma unroll
    for (int s = 8; s >= 1; s >>= 1) {
        if (ty < s) {
            #pragma unroll
            for (int j = 0; j < 8; ++j)
                redu[ty][tx * 8 + j] += redu[ty + s][tx * 8 + j];
        }
        __syncthreads();
    }

    // ---- global block: u_new[g] = relu([u | pooled/cnt] @ Wu + bu) ----
    float cnt = fmaxf((float)(end - start), 1.0f);
    if (tid < 64)        cat[tid] = u[g * 64 + tid];
    else if (tid < 192)  cat[tid] = redu[0][tid - 64] / cnt;
    __syncthreads();
    if (tid < 64) {
        float acc = bu[tid];
        #pragma unroll 4
        for (int k = 0; k < 192; ++k)
            acc = fmaf(cat[k], Wu[k * 64 + tid], acc);
        out[g * 64 + tid] = fmaxf(acc, 0.f);
    }
}

// ---------------------------------------------------------------------------
extern "C" void kernel_launch(void* const* d_in, const int* in_sizes, int n_in,
                              void* d_out, int out_size, void* d_ws, size_t ws_size,
                              hipStream_t stream) {
    const float* x     = (const float*)d_in[0];
    const int*   eidx  = (const int*)d_in[1];
    const float* eattr = (const float*)d_in[2];
    const float* u     = (const float*)d_in[3];
    const int*   batch = (const int*)d_in[4];
    const float* We1   = (const float*)d_in[5];
    const float* be1   = (const float*)d_in[6];
    const float* We2   = (const float*)d_in[7];
    const float* be2   = (const float*)d_in[8];
    const float* Wg    = (const float*)d_in[9];
    const float* bg    = (const float*)d_in[10];
    const float* Wn    = (const float*)d_in[11];
    const float* bn    = (const float*)d_in[12];
    const float* Wu    = (const float*)d_in[13];
    const float* bu    = (const float*)d_in[14];

    float* out    = (float*)d_out;                 // chunk 0: u_new [512*64] fp32
    float* xw_out = out + N_GRAPHS * D_GLOB;       // chunk 1: x_weights [50000*128] fp32
    float* agg    = xw_out;                        // fp32 agg aliases chunk 1 (exact fit)

    // zero the agg region (d_out is re-poisoned before every timed launch)
    hipMemsetAsync(xw_out, 0, (size_t)N_NODES * D_HID * sizeof(float), stream);

    edge_kernel<<<N_EDGES / 32, 256, 0, stream>>>(x, eidx, eattr, We1, be1, We2, be2, agg);
    node_global_kernel<<<N_GRAPHS, 256, 0, stream>>>(x, agg, batch, Wg, bg, Wn, bn,
                                                     u, Wu, bu, xw_out, out);
}